// Round 1
// baseline (2105.898 us; speedup 1.0000x reference)
//
#include <hip/hip_runtime.h>
#include <math.h>

#define BS 8192
#define HID 256
#define SPB1 8

// ---- workspace layout (float element offsets) ----
#define WT1_OFF 0
#define WT2_OFF 65536
#define WT3_OFF 131072
#define WT0_OFF 196608
#define S_OFF   204800
#define C_OFF   (S_OFF + 4 * BS * HID)
#define G_OFF   (C_OFF + 4 * BS * HID)
// total: G_OFF + BS*16 = 17,113,088 floats = ~65.3 MiB

__device__ __forceinline__ void silu_derivs(float a, float& h, float& sp, float& fpp) {
    float sig = 1.0f / (1.0f + __expf(-a));
    float om  = 1.0f - sig;
    h   = a * sig;
    sp  = sig * (1.0f + a * om);                       // silu'
    fpp = sig * om * (2.0f + a * (1.0f - 2.0f * sig)); // silu''
}

// ---------------- kernel 0: weight transposes ----------------
__global__ void k_transpose(const float* __restrict__ W0, const float* __restrict__ W1,
                            const float* __restrict__ W2, const float* __restrict__ W3,
                            float* __restrict__ ws) {
    float* WT1 = ws + WT1_OFF;
    float* WT2 = ws + WT2_OFF;
    float* WT3 = ws + WT3_OFF;
    float* WT0 = ws + WT0_OFF;
    int o = blockIdx.x;      // 0..255
    int t = threadIdx.x;     // 0..255
    int which = blockIdx.y;  // 0..3
    if (which == 0)      WT1[o * 256 + t] = W1[t * 256 + o];
    else if (which == 1) WT2[o * 256 + t] = W2[t * 256 + o];
    else if (which == 2) WT3[o * 256 + t] = W3[t * 256 + o];
    else if (t < 32)     WT0[o * 32 + t]  = W0[t * 256 + o]; // WT0[i][k] = W0[k][i]
}

// ---------------- kernel 1: forward + backward (8 samples/block) ----------------
__device__ __forceinline__ void fwd_layer(int L, int t, int m0,
        const float (*Hin)[SPB1], float (*Hout)[SPB1],
        const float* __restrict__ W, const float* __restrict__ b,
        float (*F2l)[SPB1], float* __restrict__ S)
{
    float acc[SPB1];
    #pragma unroll
    for (int s = 0; s < SPB1; ++s) acc[s] = b[t];
    const float4* H4 = (const float4*)&Hin[0][0];
    #pragma unroll 4
    for (int i = 0; i < 256; ++i) {
        float w = W[i * 256 + t];
        float4 h0 = H4[i * 2 + 0];
        float4 h1 = H4[i * 2 + 1];
        acc[0] += h0.x * w; acc[1] += h0.y * w; acc[2] += h0.z * w; acc[3] += h0.w * w;
        acc[4] += h1.x * w; acc[5] += h1.y * w; acc[6] += h1.z * w; acc[7] += h1.w * w;
    }
    #pragma unroll
    for (int s = 0; s < SPB1; ++s) {
        float h, sp, fpp;
        silu_derivs(acc[s], h, sp, fpp);
        Hout[t][s] = h;
        S[(L * BS + m0 + s) * HID + t] = sp;
        F2l[t][s] = fpp;
    }
}

__device__ __forceinline__ void bwd_layer(int L, int t, int m0,
        const float (*Din)[SPB1], float (*Dout)[SPB1],
        const float* __restrict__ WT,
        const float (*F2l)[SPB1],
        const float* __restrict__ S, float* __restrict__ C)
{
    float acc[SPB1];
    #pragma unroll
    for (int s = 0; s < SPB1; ++s) acc[s] = 0.0f;
    const float4* D4 = (const float4*)&Din[0][0];
    #pragma unroll 4
    for (int o = 0; o < 256; ++o) {
        float w = WT[o * 256 + t];
        float4 d0 = D4[o * 2 + 0];
        float4 d1 = D4[o * 2 + 1];
        acc[0] += d0.x * w; acc[1] += d0.y * w; acc[2] += d0.z * w; acc[3] += d0.w * w;
        acc[4] += d1.x * w; acc[5] += d1.y * w; acc[6] += d1.z * w; acc[7] += d1.w * w;
    }
    #pragma unroll
    for (int s = 0; s < SPB1; ++s) {
        float dh = acc[s];
        float sl = S[(L * BS + m0 + s) * HID + t];
        C[(L * BS + m0 + s) * HID + t] = dh * F2l[t][s];
        Dout[t][s] = dh * sl;  // delta_a
    }
}

__global__ __launch_bounds__(256) void k_stage1(
    const float* __restrict__ z,
    const float* __restrict__ W0, const float* __restrict__ b0,
    const float* __restrict__ W1, const float* __restrict__ b1,
    const float* __restrict__ W2, const float* __restrict__ b2,
    const float* __restrict__ W3, const float* __restrict__ b3,
    const float* __restrict__ W4,
    const float* __restrict__ WT0, const float* __restrict__ WT1,
    const float* __restrict__ WT2, const float* __restrict__ WT3,
    float* __restrict__ S, float* __restrict__ C, float* __restrict__ G)
{
    __shared__ __align__(16) float Zt[SPB1][32];
    __shared__ __align__(16) float Ha[256][SPB1];
    __shared__ __align__(16) float Hb[256][SPB1];
    __shared__ __align__(16) float F2s[4][256][SPB1];
    const int t  = threadIdx.x;
    const int m0 = blockIdx.x * SPB1;

    Zt[t >> 5][t & 31] = z[(m0 + (t >> 5)) * 32 + (t & 31)];
    __syncthreads();

    // ---- layer 1: a1 = z @ W0 + b0 ----
    {
        float acc[SPB1];
        #pragma unroll
        for (int s = 0; s < SPB1; ++s) acc[s] = b0[t];
        #pragma unroll 8
        for (int i = 0; i < 32; ++i) {
            float w = W0[i * 256 + t];
            #pragma unroll
            for (int s = 0; s < SPB1; ++s) acc[s] += Zt[s][i] * w;
        }
        #pragma unroll
        for (int s = 0; s < SPB1; ++s) {
            float h, sp, fpp;
            silu_derivs(acc[s], h, sp, fpp);
            Ha[t][s] = h;
            S[(0 * BS + m0 + s) * HID + t] = sp;
            F2s[0][t][s] = fpp;
        }
    }
    __syncthreads();
    fwd_layer(1, t, m0, Ha, Hb, W1, b1, F2s[1], S);  // h2
    __syncthreads();
    fwd_layer(2, t, m0, Hb, Ha, W2, b2, F2s[2], S);  // h3
    __syncthreads();
    // ---- layer 4 + start of backward: delta_a4 = W4col * silu'(a4), c4 = W4col * silu''(a4)
    {
        float acc[SPB1];
        #pragma unroll
        for (int s = 0; s < SPB1; ++s) acc[s] = b3[t];
        const float4* H4 = (const float4*)&Ha[0][0];
        #pragma unroll 4
        for (int i = 0; i < 256; ++i) {
            float w = W3[i * 256 + t];
            float4 h0 = H4[i * 2 + 0];
            float4 h1 = H4[i * 2 + 1];
            acc[0] += h0.x * w; acc[1] += h0.y * w; acc[2] += h0.z * w; acc[3] += h0.w * w;
            acc[4] += h1.x * w; acc[5] += h1.y * w; acc[6] += h1.z * w; acc[7] += h1.w * w;
        }
        float w4 = W4[t];
        #pragma unroll
        for (int s = 0; s < SPB1; ++s) {
            float h, sp, fpp;
            silu_derivs(acc[s], h, sp, fpp);
            Hb[t][s] = w4 * sp;                          // delta_a4
            C[(3 * BS + m0 + s) * HID + t] = w4 * fpp;   // c4
        }
    }
    __syncthreads();
    bwd_layer(2, t, m0, Hb, Ha, WT3, F2s[2], S, C);  // delta_a3 in Ha
    __syncthreads();
    bwd_layer(1, t, m0, Ha, Hb, WT2, F2s[1], S, C);  // delta_a2 in Hb
    __syncthreads();
    bwd_layer(0, t, m0, Hb, Ha, WT1, F2s[0], S, C);  // delta_a1 in Ha
    __syncthreads();
    // ---- gradient: g[k] = sum_i W0[k][i] * delta_a1[i] ----
    {
        const int k = t & 31, sh = t >> 5;  // 8 sample groups == SPB1
        float acc = 0.0f;
        #pragma unroll 4
        for (int i = 0; i < 256; ++i) acc += WT0[i * 32 + k] * Ha[i][sh];
        if (k < 16) G[(m0 + sh) * 16 + k] = acc;
    }
}

// ---------------- kernel 2: tangent propagation + Hessian block + solve ----------------
__global__ __launch_bounds__(256, 2) void k_stage2(
    const float* __restrict__ z,
    const float* __restrict__ W0,
    const float* __restrict__ W1, const float* __restrict__ W2, const float* __restrict__ W3,
    const float* __restrict__ S, const float* __restrict__ C, const float* __restrict__ G,
    float* __restrict__ out)
{
    constexpr int PAD = 260;  // 32 rows x 260 floats, 16B-aligned rows, conflict-free
    __shared__ __align__(16) float Ta[32 * PAD];
    __shared__ __align__(16) float Tb[32 * PAD];
    __shared__ __align__(16) float svec[256];
    __shared__ __align__(16) float cvec[256];
    __shared__ float HCs[32][16];
    __shared__ float Msys[16][17];
    __shared__ float fvec[16];
    __shared__ float vv[16];
    __shared__ int pivs;

    const int t = threadIdx.x;
    const int m = blockIdx.x;

    // load T1 = W0 rows (32x256) into Ta
    #pragma unroll
    for (int q = 0; q < 8; ++q) {
        int idx = q * 1024 + t * 4;
        int k = idx >> 8, i = idx & 255;
        *(float4*)&Ta[k * PAD + i] = *(const float4*)&W0[idx];
    }

    float* Tcur = Ta;
    float* Tnxt = Tb;
    float hc0 = 0.0f, hc1 = 0.0f;              // HC[kk][jp], HC[kk][jp+8]
    const int kk = t >> 3, jp = t & 7;         // contraction mapping
    const int cl = t & 31, ks = (t >> 5) & 1, rg = t >> 6;  // GEMM mapping
    const float* Wl[3] = {W1, W2, W3};

    for (int L = 0; L < 4; ++L) {
        __syncthreads();  // prior GEMM/contraction done before svec/cvec overwrite
        cvec[t] = C[(L * BS + m) * HID + t];
        if (L < 3) svec[t] = S[(L * BS + m) * HID + t];
        __syncthreads();

        // contraction: HC[k][j] += sum_i T[k][i] * c[i] * T[16+j][i]
        {
            const float4* tk4 = (const float4*)&Tcur[kk * PAD];
            const float4* tj0 = (const float4*)&Tcur[(16 + jp) * PAD];
            const float4* tj1 = (const float4*)&Tcur[(24 + jp) * PAD];
            const float4* c4v = (const float4*)cvec;
            #pragma unroll 4
            for (int ii = 0; ii < 64; ++ii) {
                float4 a  = tk4[ii];
                float4 cc = c4v[ii];
                float4 p0 = tj0[ii];
                float4 p1 = tj1[ii];
                float qx = a.x * cc.x, qy = a.y * cc.y, qz = a.z * cc.z, qw = a.w * cc.w;
                hc0 += qx * p0.x + qy * p0.y + qz * p0.z + qw * p0.w;
                hc1 += qx * p1.x + qy * p1.y + qz * p1.z + qw * p1.w;
            }
        }

        if (L < 3) {
            // GEMM: Tnxt[r][o] = sum_i (svec[i]*Tcur[r][i]) * W[i][o]
            const float* __restrict__ W = Wl[L];
            float acc[8][8];
            #pragma unroll
            for (int r = 0; r < 8; ++r)
                #pragma unroll
                for (int c = 0; c < 8; ++c) acc[r][c] = 0.0f;
            const int i0 = ks * 128;
            for (int ic = 0; ic < 32; ++ic) {
                const int i = i0 + ic * 4;
                float4 sv = *(const float4*)&svec[i];
                float hs[8][4];
                #pragma unroll
                for (int r = 0; r < 8; ++r) {
                    float4 tv = *(const float4*)&Tcur[(rg * 8 + r) * PAD + i];
                    hs[r][0] = tv.x * sv.x; hs[r][1] = tv.y * sv.y;
                    hs[r][2] = tv.z * sv.z; hs[r][3] = tv.w * sv.w;
                }
                #pragma unroll
                for (int d = 0; d < 4; ++d) {
                    float wv[8];
                    #pragma unroll
                    for (int cc = 0; cc < 8; ++cc) wv[cc] = W[(i + d) * 256 + cl + 32 * cc];
                    #pragma unroll
                    for (int r = 0; r < 8; ++r)
                        #pragma unroll
                        for (int cc = 0; cc < 8; ++cc)
                            acc[r][cc] += hs[r][d] * wv[cc];
                }
            }
            #pragma unroll
            for (int r = 0; r < 8; ++r) {
                #pragma unroll
                for (int cc = 0; cc < 8; ++cc) {
                    float v2 = acc[r][cc] + __shfl_xor(acc[r][cc], 32, 64);
                    if (ks == 0) Tnxt[(rg * 8 + r) * PAD + cl + 32 * cc] = v2;
                }
            }
            float* tmp = Tcur; Tcur = Tnxt; Tnxt = tmp;
        }
    }

    // ---- assemble and solve ----
    HCs[kk][jp]     = hc0;
    HCs[kk][jp + 8] = hc1;
    if (t < 16) vv[t] = z[m * 32 + 16 + t];
    __syncthreads();
    {
        int i = t >> 4, j = t & 15;
        Msys[i][j] = HCs[16 + i][j] + (i == j ? 0.2f : 0.0f);  // H_pp
    }
    if (t < 16) {
        float r = G[m * 16 + t];
        #pragma unroll
        for (int j = 0; j < 16; ++j) r -= HCs[j][t] * vv[j];   // - H[16+t][j] v[j]
        Msys[t][16] = r;
    }
    __syncthreads();
    // Gauss-Jordan with partial pivoting
    for (int k2 = 0; k2 < 16; ++k2) {
        if (t == 0) {
            int p = k2; float best = fabsf(Msys[k2][k2]);
            for (int r = k2 + 1; r < 16; ++r) {
                float v = fabsf(Msys[r][k2]);
                if (v > best) { best = v; p = r; }
            }
            pivs = p;
        }
        __syncthreads();
        const int p = pivs;
        if (p != k2 && t < 17) {
            float tmp = Msys[k2][t]; Msys[k2][t] = Msys[p][t]; Msys[p][t] = tmp;
        }
        __syncthreads();
        if (t < 16) fvec[t] = (t == k2) ? 0.0f : Msys[t][k2] / Msys[k2][k2];
        __syncthreads();
        {
            int r = t >> 4, c = t & 15;
            if (r != k2) Msys[r][c] -= fvec[r] * Msys[k2][c];
        }
        if (t < 16 && t != k2) Msys[t][16] -= fvec[t] * Msys[k2][16];
        __syncthreads();
    }
    if (t < 16) {
        out[m * 32 + t]      = vv[t];                      // v
        out[m * 32 + 16 + t] = Msys[t][16] / Msys[t][t];   // a
    }
}

extern "C" void kernel_launch(void* const* d_in, const int* in_sizes, int n_in,
                              void* d_out, int out_size, void* d_ws, size_t ws_size,
                              hipStream_t stream) {
    const float* z  = (const float*)d_in[1];
    const float* W0 = (const float*)d_in[2];
    const float* b0 = (const float*)d_in[3];
    const float* W1 = (const float*)d_in[4];
    const float* b1 = (const float*)d_in[5];
    const float* W2 = (const float*)d_in[6];
    const float* b2 = (const float*)d_in[7];
    const float* W3 = (const float*)d_in[8];
    const float* b3 = (const float*)d_in[9];
    const float* W4 = (const float*)d_in[10];
    float* out = (float*)d_out;
    float* ws  = (float*)d_ws;

    float* WT1 = ws + WT1_OFF;
    float* WT2 = ws + WT2_OFF;
    float* WT3 = ws + WT3_OFF;
    float* WT0 = ws + WT0_OFF;
    float* S   = ws + S_OFF;
    float* C   = ws + C_OFF;
    float* G   = ws + G_OFF;

    k_transpose<<<dim3(256, 4), 256, 0, stream>>>(W0, W1, W2, W3, ws);
    k_stage1<<<BS / SPB1, 256, 0, stream>>>(z, W0, b0, W1, b1, W2, b2, W3, b3, W4,
                                            WT0, WT1, WT2, WT3, S, C, G);
    k_stage2<<<BS, 256, 0, stream>>>(z, W0, W1, W2, W3, S, C, G, out);
}

// Round 2
// 1375.005 us; speedup vs baseline: 1.5316x; 1.5316x over previous
//
#include <hip/hip_runtime.h>
#include <math.h>

#define BS 8192
#define HID 256
#define SPB1 8

// ---- workspace layout (float element offsets) ----
#define WT1_OFF 0
#define WT2_OFF 65536
#define WT3_OFF 131072
#define WT0_OFF 196608
#define S_OFF   204800
#define C_OFF   (S_OFF + 4 * BS * HID)
#define G_OFF   (C_OFF + 4 * BS * HID)
#define WBT_OFF (G_OFF + BS * 16)
// WBT region: 3 layers x 2 (hi,lo) x 256 x 256 ushort = 786432 B after WBT_OFF floats

typedef __attribute__((ext_vector_type(8))) short bf16x8;
typedef __attribute__((ext_vector_type(4))) float f32x4;
#define MFMA16(A, B, C) __builtin_amdgcn_mfma_f32_16x16x32_bf16(A, B, C, 0, 0, 0)

__device__ __forceinline__ ushort bf16_rne(float x) {
    unsigned u = __float_as_uint(x);
    unsigned r = u + 0x7FFFu + ((u >> 16) & 1u);
    return (ushort)(r >> 16);
}
__device__ __forceinline__ void bsplit(float x, ushort& hi, ushort& lo) {
    hi = bf16_rne(x);
    float hf = __uint_as_float(((unsigned)hi) << 16);
    lo = bf16_rne(x - hf);
}

__device__ __forceinline__ void silu_derivs(float a, float& h, float& sp, float& fpp) {
    float sig = 1.0f / (1.0f + __expf(-a));
    float om  = 1.0f - sig;
    h   = a * sig;
    sp  = sig * (1.0f + a * om);                       // silu'
    fpp = sig * om * (2.0f + a * (1.0f - 2.0f * sig)); // silu''
}

// ---------------- kernel 0: weight transposes + bf16 hi/lo split ----------------
__global__ void k_transpose(const float* __restrict__ W0, const float* __restrict__ W1,
                            const float* __restrict__ W2, const float* __restrict__ W3,
                            float* __restrict__ ws) {
    float* WT1 = ws + WT1_OFF;
    float* WT2 = ws + WT2_OFF;
    float* WT3 = ws + WT3_OFF;
    float* WT0 = ws + WT0_OFF;
    ushort* WBT = (ushort*)(ws + WBT_OFF);
    int o = blockIdx.x;      // 0..255
    int t = threadIdx.x;     // 0..255
    int which = blockIdx.y;  // 0..3
    if (which < 3) {
        const float* W = (which == 0) ? W1 : (which == 1) ? W2 : W3;
        float* WT = (which == 0) ? WT1 : (which == 1) ? WT2 : WT3;
        float v = W[t * 256 + o];
        WT[o * 256 + t] = v;
        ushort h, l;
        bsplit(v, h, l);
        WBT[(which * 2 + 0) * 65536 + o * 256 + t] = h;  // W^T hi: [n][k]
        WBT[(which * 2 + 1) * 65536 + o * 256 + t] = l;  // W^T lo
    } else if (t < 32) {
        WT0[o * 32 + t] = W0[t * 256 + o]; // WT0[i][k] = W0[k][i]
    }
}

// ---------------- kernel 1: forward + backward (8 samples/block) ----------------
__device__ __forceinline__ void fwd_layer(int L, int t, int m0,
        const float (*Hin)[SPB1], float (*Hout)[SPB1],
        const float* __restrict__ W, const float* __restrict__ b,
        float (*F2l)[SPB1], float* __restrict__ S)
{
    float acc[SPB1];
    #pragma unroll
    for (int s = 0; s < SPB1; ++s) acc[s] = b[t];
    const float4* H4 = (const float4*)&Hin[0][0];
    #pragma unroll 4
    for (int i = 0; i < 256; ++i) {
        float w = W[i * 256 + t];
        float4 h0 = H4[i * 2 + 0];
        float4 h1 = H4[i * 2 + 1];
        acc[0] += h0.x * w; acc[1] += h0.y * w; acc[2] += h0.z * w; acc[3] += h0.w * w;
        acc[4] += h1.x * w; acc[5] += h1.y * w; acc[6] += h1.z * w; acc[7] += h1.w * w;
    }
    #pragma unroll
    for (int s = 0; s < SPB1; ++s) {
        float h, sp, fpp;
        silu_derivs(acc[s], h, sp, fpp);
        Hout[t][s] = h;
        S[(L * BS + m0 + s) * HID + t] = sp;
        F2l[t][s] = fpp;
    }
}

__device__ __forceinline__ void bwd_layer(int L, int t, int m0,
        const float (*Din)[SPB1], float (*Dout)[SPB1],
        const float* __restrict__ WT,
        const float (*F2l)[SPB1],
        const float* __restrict__ S, float* __restrict__ C)
{
    float acc[SPB1];
    #pragma unroll
    for (int s = 0; s < SPB1; ++s) acc[s] = 0.0f;
    const float4* D4 = (const float4*)&Din[0][0];
    #pragma unroll 4
    for (int o = 0; o < 256; ++o) {
        float w = WT[o * 256 + t];
        float4 d0 = D4[o * 2 + 0];
        float4 d1 = D4[o * 2 + 1];
        acc[0] += d0.x * w; acc[1] += d0.y * w; acc[2] += d0.z * w; acc[3] += d0.w * w;
        acc[4] += d1.x * w; acc[5] += d1.y * w; acc[6] += d1.z * w; acc[7] += d1.w * w;
    }
    #pragma unroll
    for (int s = 0; s < SPB1; ++s) {
        float dh = acc[s];
        float sl = S[(L * BS + m0 + s) * HID + t];
        C[(L * BS + m0 + s) * HID + t] = dh * F2l[t][s];
        Dout[t][s] = dh * sl;  // delta_a
    }
}

__global__ __launch_bounds__(256) void k_stage1(
    const float* __restrict__ z,
    const float* __restrict__ W0, const float* __restrict__ b0,
    const float* __restrict__ W1, const float* __restrict__ b1,
    const float* __restrict__ W2, const float* __restrict__ b2,
    const float* __restrict__ W3, const float* __restrict__ b3,
    const float* __restrict__ W4,
    const float* __restrict__ WT0, const float* __restrict__ WT1,
    const float* __restrict__ WT2, const float* __restrict__ WT3,
    float* __restrict__ S, float* __restrict__ C, float* __restrict__ G)
{
    __shared__ __align__(16) float Zt[SPB1][32];
    __shared__ __align__(16) float Ha[256][SPB1];
    __shared__ __align__(16) float Hb[256][SPB1];
    __shared__ __align__(16) float F2s[4][256][SPB1];
    const int t  = threadIdx.x;
    const int m0 = blockIdx.x * SPB1;

    Zt[t >> 5][t & 31] = z[(m0 + (t >> 5)) * 32 + (t & 31)];
    __syncthreads();

    // ---- layer 1: a1 = z @ W0 + b0 ----
    {
        float acc[SPB1];
        #pragma unroll
        for (int s = 0; s < SPB1; ++s) acc[s] = b0[t];
        #pragma unroll 8
        for (int i = 0; i < 32; ++i) {
            float w = W0[i * 256 + t];
            #pragma unroll
            for (int s = 0; s < SPB1; ++s) acc[s] += Zt[s][i] * w;
        }
        #pragma unroll
        for (int s = 0; s < SPB1; ++s) {
            float h, sp, fpp;
            silu_derivs(acc[s], h, sp, fpp);
            Ha[t][s] = h;
            S[(0 * BS + m0 + s) * HID + t] = sp;
            F2s[0][t][s] = fpp;
        }
    }
    __syncthreads();
    fwd_layer(1, t, m0, Ha, Hb, W1, b1, F2s[1], S);  // h2
    __syncthreads();
    fwd_layer(2, t, m0, Hb, Ha, W2, b2, F2s[2], S);  // h3
    __syncthreads();
    // ---- layer 4 + start of backward ----
    {
        float acc[SPB1];
        #pragma unroll
        for (int s = 0; s < SPB1; ++s) acc[s] = b3[t];
        const float4* H4 = (const float4*)&Ha[0][0];
        #pragma unroll 4
        for (int i = 0; i < 256; ++i) {
            float w = W3[i * 256 + t];
            float4 h0 = H4[i * 2 + 0];
            float4 h1 = H4[i * 2 + 1];
            acc[0] += h0.x * w; acc[1] += h0.y * w; acc[2] += h0.z * w; acc[3] += h0.w * w;
            acc[4] += h1.x * w; acc[5] += h1.y * w; acc[6] += h1.z * w; acc[7] += h1.w * w;
        }
        float w4 = W4[t];
        #pragma unroll
        for (int s = 0; s < SPB1; ++s) {
            float h, sp, fpp;
            silu_derivs(acc[s], h, sp, fpp);
            Hb[t][s] = w4 * sp;                          // delta_a4
            C[(3 * BS + m0 + s) * HID + t] = w4 * fpp;   // c4
        }
    }
    __syncthreads();
    bwd_layer(2, t, m0, Hb, Ha, WT3, F2s[2], S, C);  // delta_a3 in Ha
    __syncthreads();
    bwd_layer(1, t, m0, Ha, Hb, WT2, F2s[1], S, C);  // delta_a2 in Hb
    __syncthreads();
    bwd_layer(0, t, m0, Hb, Ha, WT1, F2s[0], S, C);  // delta_a1 in Ha
    __syncthreads();
    // ---- gradient ----
    {
        const int k = t & 31, sh = t >> 5;
        float acc = 0.0f;
        #pragma unroll 4
        for (int i = 0; i < 256; ++i) acc += WT0[i * 32 + k] * Ha[i][sh];
        if (k < 16) G[(m0 + sh) * 16 + k] = acc;
    }
}

// ---------------- kernel 2: MFMA tangent propagation + Hessian + solve ----------------
// 2 samples / block, 256 threads = 4 waves. K-phase-split arrays (128 cols resident).
#define RS 136   // row stride in shorts (272 B): 16B-aligned rows, even bank spread

__global__ __launch_bounds__(256, 1) void k_stage2(
    const float* __restrict__ z,
    const float* __restrict__ W0,
    const ushort* __restrict__ WBT,
    const float* __restrict__ S, const float* __restrict__ C, const float* __restrict__ G,
    float* __restrict__ out)
{
    __shared__ __align__(16) ushort ASh[2][32][RS], ASl[2][32][RS];  // split(s (.) T)
    __shared__ __align__(16) ushort ACh[2][32][RS], ACl[2][32][RS];  // split(c (.) T)
    __shared__ __align__(16) ushort TPh[2][16][RS], TPl[2][16][RS];  // split(T rows 16..31)
    __shared__ float Msys2[2][16][17];
    __shared__ float vv2[2][16];

    // overlays (dead AS regions reused after last GEMM)
    float* HCp = (float*)&ASh[0][0][0];   // [2][4 waves][2 dt][16][16] partials (16 KB)
    float* HCm = (float*)&ASl[0][0][0];   // [2][32][16] reduced (4 KB)

    const int t    = threadIdx.x;
    const int m0   = blockIdx.x * 2;
    const int lane = t & 63;
    const int w    = t >> 6;       // wave id 0..3
    const int l15  = lane & 15;
    const int q    = lane >> 4;    // 0..3
    const int koff = q * 8;

    f32x4 Tacc[2][2][4];   // [sample][mg][ntile-idx] current-layer T tiles
    f32x4 Tnxt[2][2][4];
    f32x4 Dacc[2][2];      // [sample][dt] Hessian-block accumulators

    #pragma unroll
    for (int s = 0; s < 2; ++s) {
        #pragma unroll
        for (int mg = 0; mg < 2; ++mg)
            #pragma unroll
            for (int ni = 0; ni < 4; ++ni)
                #pragma unroll
                for (int r = 0; r < 4; ++r) { Tnxt[s][mg][ni][r] = 0.0f; Tacc[s][mg][ni][r] = 0.0f; }
        #pragma unroll
        for (int dt = 0; dt < 2; ++dt)
            #pragma unroll
            for (int r = 0; r < 4; ++r) Dacc[s][dt][r] = 0.0f;
    }

    for (int lay = 0; lay < 4; ++lay) {
        #pragma unroll
        for (int ph = 0; ph < 2; ++ph) {
            // ---------- epilogue: write split arrays for this phase's cols ----------
            if (lay == 0) {
                // T_1 = W0 (sample-independent values, per-sample scaling)
                const int c    = t & 127;
                const int half = t >> 7;
                const int cg   = ph * 128 + c;
                float svv[2], cvv[2];
                #pragma unroll
                for (int s = 0; s < 2; ++s) {
                    svv[s] = S[(0 * BS + m0 + s) * HID + cg];
                    cvv[s] = C[(0 * BS + m0 + s) * HID + cg];
                }
                #pragma unroll
                for (int e = 0; e < 16; ++e) {
                    const int r = half * 16 + e;
                    float w0 = W0[r * HID + cg];
                    ushort th, tl;
                    bsplit(w0, th, tl);
                    #pragma unroll
                    for (int s = 0; s < 2; ++s) {
                        ushort h1, l1, h2, l2;
                        bsplit(svv[s] * w0, h1, l1);
                        bsplit(cvv[s] * w0, h2, l2);
                        ASh[s][r][c] = h1; ASl[s][r][c] = l1;
                        ACh[s][r][c] = h2; ACl[s][r][c] = l2;
                        if (half == 1) { TPh[s][r - 16][c] = th; TPl[s][r - 16][c] = tl; }
                    }
                }
            } else {
                #pragma unroll
                for (int ni = 0; ni < 2; ++ni) {
                    const int nti = ph * 2 + ni;
                    const int cg  = (w + 4 * nti) * 16 + l15;
                    const int cl  = cg - ph * 128;
                    #pragma unroll
                    for (int s = 0; s < 2; ++s) {
                        const float sv = (lay < 3) ? S[(lay * BS + m0 + s) * HID + cg] : 0.0f;
                        const float cv = C[(lay * BS + m0 + s) * HID + cg];
                        #pragma unroll
                        for (int mg = 0; mg < 2; ++mg) {
                            #pragma unroll
                            for (int rg = 0; rg < 4; ++rg) {
                                const int row = mg * 16 + q * 4 + rg;
                                const float tv = Tacc[s][mg][nti][rg];
                                ushort h, l;
                                if (lay < 3) {
                                    bsplit(sv * tv, h, l);
                                    ASh[s][row][cl] = h; ASl[s][row][cl] = l;
                                }
                                bsplit(cv * tv, h, l);
                                ACh[s][row][cl] = h; ACl[s][row][cl] = l;
                                if (mg == 1) {
                                    bsplit(tv, h, l);
                                    TPh[s][row - 16][cl] = h; TPl[s][row - 16][cl] = l;
                                }
                            }
                        }
                    }
                }
            }
            __syncthreads();

            // ---------- contraction: D += (c.T)·Tp^T over this wave's K-chunk ----------
            {
                const int kb = w * 32 + koff;
                #pragma unroll
                for (int s = 0; s < 2; ++s) {
                    bf16x8 Bh = *(const bf16x8*)&TPh[s][l15][kb];
                    bf16x8 Bl = *(const bf16x8*)&TPl[s][l15][kb];
                    #pragma unroll
                    for (int dt = 0; dt < 2; ++dt) {
                        bf16x8 Ah = *(const bf16x8*)&ACh[s][dt * 16 + l15][kb];
                        bf16x8 Al = *(const bf16x8*)&ACl[s][dt * 16 + l15][kb];
                        f32x4 d = Dacc[s][dt];
                        d = MFMA16(Ah, Bh, d);
                        d = MFMA16(Al, Bh, d);
                        d = MFMA16(Ah, Bl, d);
                        d = MFMA16(Al, Bl, d);
                        Dacc[s][dt] = d;
                    }
                }
            }

            // ---------- GEMM: Tnxt += (s.T) @ W_{lay+1} over this phase's K ----------
            if (lay < 3) {
                const ushort* WH = WBT + (lay * 2 + 0) * 65536;
                const ushort* WL = WBT + (lay * 2 + 1) * 65536;
                #pragma unroll
                for (int kst = 0; kst < 4; ++kst) {
                    const int kl = kst * 32 + koff;
                    const int kg = ph * 128 + kl;
                    bf16x8 Ah[2][2], Al[2][2];
                    #pragma unroll
                    for (int s = 0; s < 2; ++s)
                        #pragma unroll
                        for (int mg = 0; mg < 2; ++mg) {
                            Ah[s][mg] = *(const bf16x8*)&ASh[s][mg * 16 + l15][kl];
                            Al[s][mg] = *(const bf16x8*)&ASl[s][mg * 16 + l15][kl];
                        }
                    #pragma unroll
                    for (int ni = 0; ni < 4; ++ni) {
                        const int nrow = (w + 4 * ni) * 16 + l15;
                        bf16x8 Bh = *(const bf16x8*)(WH + nrow * 256 + kg);
                        bf16x8 Bl = *(const bf16x8*)(WL + nrow * 256 + kg);
                        #pragma unroll
                        for (int s = 0; s < 2; ++s)
                            #pragma unroll
                            for (int mg = 0; mg < 2; ++mg) {
                                f32x4 cc = Tnxt[s][mg][ni];
                                cc = MFMA16(Ah[s][mg], Bh, cc);
                                cc = MFMA16(Al[s][mg], Bh, cc);
                                cc = MFMA16(Ah[s][mg], Bl, cc);
                                cc = MFMA16(Al[s][mg], Bl, cc);
                                Tnxt[s][mg][ni] = cc;
                            }
                    }
                }
            }
        } // ph

        if (lay < 3) {
            #pragma unroll
            for (int s = 0; s < 2; ++s)
                #pragma unroll
                for (int mg = 0; mg < 2; ++mg)
                    #pragma unroll
                    for (int ni = 0; ni < 4; ++ni) {
                        Tacc[s][mg][ni] = Tnxt[s][mg][ni];
                        #pragma unroll
                        for (int r = 0; r < 4; ++r) Tnxt[s][mg][ni][r] = 0.0f;
                    }
        }
    } // lay

    // ---------- reduce Hessian partials ----------
    __syncthreads();  // all AS reads long done; safe to overlay
    #pragma unroll
    for (int s = 0; s < 2; ++s)
        #pragma unroll
        for (int dt = 0; dt < 2; ++dt)
            #pragma unroll
            for (int rg = 0; rg < 4; ++rg)
                HCp[((s * 4 + w) * 2 + dt) * 256 + (q * 4 + rg) * 16 + l15] = Dacc[s][dt][rg];
    __syncthreads();
    for (int e = t; e < 1024; e += 256) {
        const int s = e >> 9, k = (e >> 4) & 31, j = e & 15;
        const int dt = k >> 4, kr = k & 15;
        float acc = 0.0f;
        #pragma unroll
        for (int wv = 0; wv < 4; ++wv) acc += HCp[((s * 4 + wv) * 2 + dt) * 256 + kr * 16 + j];
        HCm[(s * 32 + k) * 16 + j] = acc;
    }
    __syncthreads();

    // ---------- per-wave 16x16 solve (waves 0,1 <-> samples 0,1) ----------
    if (w < 2) {
        const int s = w;
        float* M = &Msys2[s][0][0];   // [16][17]
        float vr = 0.0f;
        if (lane < 16) {
            vr = z[(m0 + s) * 32 + 16 + lane];
            vv2[s][lane] = vr;
        }
        if (lane < 16) {
            #pragma unroll
            for (int j = 0; j < 16; ++j)
                M[lane * 17 + j] = HCm[(s * 32 + 16 + lane) * 16 + j] + (lane == j ? 0.2f : 0.0f);
            float r = G[(m0 + s) * 16 + lane];
            #pragma unroll
            for (int j = 0; j < 16; ++j)
                r -= HCm[(s * 32 + j) * 16 + lane] * vv2[s][j];
            M[lane * 17 + 16] = r;
        }
        // Gauss-Jordan with partial pivoting (wave-synchronous, no barriers)
        for (int k2 = 0; k2 < 16; ++k2) {
            float val = (lane < 16 && lane >= k2) ? fabsf(M[lane * 17 + k2]) : -1.0f;
            int idx = lane;
            #pragma unroll
            for (int off = 8; off > 0; off >>= 1) {
                float ov = __shfl_xor(val, off, 64);
                int oi = __shfl_xor(idx, off, 64);
                if (ov > val) { val = ov; idx = oi; }
            }
            const int p = __shfl(idx, 0, 64);
            if (p != k2 && lane < 17) {
                float tmp = M[k2 * 17 + lane];
                M[k2 * 17 + lane] = M[p * 17 + lane];
                M[p * 17 + lane] = tmp;
            }
            if (lane < 16) {
                const float f = (lane == k2) ? 0.0f : M[lane * 17 + k2] / M[k2 * 17 + k2];
                #pragma unroll
                for (int j = 0; j < 17; ++j)
                    M[lane * 17 + j] -= f * M[k2 * 17 + j];
            }
        }
        if (lane < 16) {
            out[(m0 + s) * 32 + lane]      = vr;
            out[(m0 + s) * 32 + 16 + lane] = M[lane * 17 + 16] / M[lane * 17 + lane];
        }
    }
}

extern "C" void kernel_launch(void* const* d_in, const int* in_sizes, int n_in,
                              void* d_out, int out_size, void* d_ws, size_t ws_size,
                              hipStream_t stream) {
    const float* z  = (const float*)d_in[1];
    const float* W0 = (const float*)d_in[2];
    const float* b0 = (const float*)d_in[3];
    const float* W1 = (const float*)d_in[4];
    const float* b1 = (const float*)d_in[5];
    const float* W2 = (const float*)d_in[6];
    const float* b2 = (const float*)d_in[7];
    const float* W3 = (const float*)d_in[8];
    const float* b3 = (const float*)d_in[9];
    const float* W4 = (const float*)d_in[10];
    float* out = (float*)d_out;
    float* ws  = (float*)d_ws;

    float* WT1 = ws + WT1_OFF;
    float* WT2 = ws + WT2_OFF;
    float* WT3 = ws + WT3_OFF;
    float* WT0 = ws + WT0_OFF;
    float* S   = ws + S_OFF;
    float* C   = ws + C_OFF;
    float* G   = ws + G_OFF;
    const ushort* WBT = (const ushort*)(ws + WBT_OFF);

    k_transpose<<<dim3(256, 4), 256, 0, stream>>>(W0, W1, W2, W3, ws);
    k_stage1<<<BS / SPB1, 256, 0, stream>>>(z, W0, b0, W1, b1, W2, b2, W3, b3, W4,
                                            WT0, WT1, WT2, WT3, S, C, G);
    k_stage2<<<BS / 2, 256, 0, stream>>>(z, W0, WBT, S, C, G, out);
}